// Round 3
// baseline (441.556 us; speedup 1.0000x reference)
//
#include <hip/hip_runtime.h>
#include <math.h>

constexpr int HD    = 32;     // head dim
constexpr int LW    = 256;    // tokens per window (M * N_CAND)
constexpr int NWIN  = 128;    // number of windows (= B_)
constexpr int ROWS  = NWIN * LW;   // 32768 total rows
constexpr int QKVC  = 384;    // qkv columns
constexpr float SCALE = 0.17677669529663687f;  // 1/sqrt(32)

__device__ inline float dot4(const float4 a, const float4 b) {
  return a.x * b.x + a.y * b.y + a.z * b.z + a.w * b.w;
}

// ---------------- RPE gather: rpe_g[h][i4*64+j4][0:96] ----------------
// s in [0,32): scale*q_rpe   [32,64): k_rpe   [64,96): v_rpe
__global__ __launch_bounds__(256) void rpe_gather_kernel(
    const float* __restrict__ tab, const int* __restrict__ rel_idx,
    float* __restrict__ out)
{
  int gid = blockIdx.x * 256 + threadIdx.x;   // 4*4096*96 = 1,572,864 exact
  int s   = gid % 96;
  int hp  = gid / 96;
  int p   = hp & 4095;
  int h   = hp >> 12;
  float v = tab[(size_t)rel_idx[p] * 384 + h * 96 + s];
  if (s < 32) v *= SCALE;
  out[gid] = v;
}

// ---------------- C[M,N] = A[M,K] @ W[N,K]^T + bias (LDS dbuf v3) -----------
template <int N, int K>
__global__ __launch_bounds__(256) void gemm_nt_bias_v3(
    const float* __restrict__ A, const float* __restrict__ W,
    const float* __restrict__ bias, float* __restrict__ C)
{
  constexpr int BK  = 8;
  constexpr int NS  = K / BK;
  constexpr int LDP = 144;
  __shared__ float As[2][BK][LDP];
  __shared__ float Ws[2][BK][LDP];

  const int tid  = threadIdx.x;
  const int tx   = tid & 15;          // n-dir, 8 cols each
  const int ty   = tid >> 4;          // m-dir, 8 rows each
  const int srow = tid >> 1;          // staging row 0..127
  const int skk  = (tid & 1) << 2;    // staging k base: 0 or 4
  const int sphys = srow + ((srow >> 5) << 2);

  const float* Ag = A + ((size_t)blockIdx.x * 128 + srow) * K + skk;
  const float* Wg = W + ((size_t)blockIdx.y * 128 + srow) * K + skk;

  float4 ra = *(const float4*)(Ag);
  float4 rw = *(const float4*)(Wg);
  As[0][skk + 0][sphys] = ra.x; As[0][skk + 1][sphys] = ra.y;
  As[0][skk + 2][sphys] = ra.z; As[0][skk + 3][sphys] = ra.w;
  Ws[0][skk + 0][sphys] = rw.x; Ws[0][skk + 1][sphys] = rw.y;
  Ws[0][skk + 2][sphys] = rw.z; Ws[0][skk + 3][sphys] = rw.w;
  __syncthreads();

  const int mA = ty * 8; const int pA = mA + ((mA >> 5) << 2);
  const int mB = tx * 8; const int pB = mB + ((mB >> 5) << 2);

  float acc[8][8] = {};

  for (int s = 0; s < NS; ++s) {
    const int cur = s & 1;
    if (s + 1 < NS) {
      const int k0 = (s + 1) * BK;
      ra = *(const float4*)(Ag + k0);
      rw = *(const float4*)(Wg + k0);
    }
#pragma unroll
    for (int k = 0; k < BK; ++k) {
      float4 a0 = *(const float4*)&As[cur][k][pA];
      float4 a1 = *(const float4*)&As[cur][k][pA + 4];
      float4 b0 = *(const float4*)&Ws[cur][k][pB];
      float4 b1 = *(const float4*)&Ws[cur][k][pB + 4];
      float av[8] = {a0.x, a0.y, a0.z, a0.w, a1.x, a1.y, a1.z, a1.w};
      float bv[8] = {b0.x, b0.y, b0.z, b0.w, b1.x, b1.y, b1.z, b1.w};
#pragma unroll
      for (int i = 0; i < 8; ++i)
#pragma unroll
        for (int j = 0; j < 8; ++j)
          acc[i][j] += av[i] * bv[j];
    }
    if (s + 1 < NS) {
      const int nxt = (s + 1) & 1;
      As[nxt][skk + 0][sphys] = ra.x; As[nxt][skk + 1][sphys] = ra.y;
      As[nxt][skk + 2][sphys] = ra.z; As[nxt][skk + 3][sphys] = ra.w;
      Ws[nxt][skk + 0][sphys] = rw.x; Ws[nxt][skk + 1][sphys] = rw.y;
      Ws[nxt][skk + 2][sphys] = rw.z; Ws[nxt][skk + 3][sphys] = rw.w;
      __syncthreads();
    }
  }

  const int crow = blockIdx.x * 128 + ty * 8;
  const int ccol = blockIdx.y * 128 + tx * 8;
  float4 bb0 = *(const float4*)(bias + ccol);
  float4 bb1 = *(const float4*)(bias + ccol + 4);
#pragma unroll
  for (int i = 0; i < 8; ++i) {
    float4 r0, r1;
    r0.x = acc[i][0] + bb0.x; r0.y = acc[i][1] + bb0.y;
    r0.z = acc[i][2] + bb0.z; r0.w = acc[i][3] + bb0.w;
    r1.x = acc[i][4] + bb1.x; r1.y = acc[i][5] + bb1.y;
    r1.z = acc[i][6] + bb1.z; r1.w = acc[i][7] + bb1.w;
    *(float4*)(C + (size_t)(crow + i) * N + ccol)     = r0;
    *(float4*)(C + (size_t)(crow + i) * N + ccol + 4) = r1;
  }
}

// ------------- fused window attention (v4: cross-block j-split) -------------
// grid (NWIN, 4 heads, 2 j-halves), 256 threads. Block z stages only its
// K/V half -> LDS 32 KB, so 4 blocks/CU fit. __launch_bounds__(256,4):
// empirically the 2nd arg pins waves/SIMD (v2: (512,4)->41.6%, v3:
// (512,2)->22.1%); for 4-wave blocks it caps VGPR at 512/4=128 which the
// natural ~90-110 allocation fits (NO spill -- v2's (512,4) cap was 64 and
// spilled: FETCH 66->145MB). Target: 16 waves/CU, occupancy ~50%.
// Each block computes an online-softmax PARTIAL (m, l, acc[32]) over its 32
// j4 blocks; partials land in workspace (comp-major, coalesced) and a tiny
// merge kernel combines the two halves.
// Hot-loop changes vs v3: rescale once per j4 (max of 4 scores) instead of
// per-jc; u folded into the d-loop (transient, -32 regs); v_rpe fused into
// the PV pass (5-FMA/elem single pass).
__global__ __launch_bounds__(256, 4) void attn_kernel(
    const float* __restrict__ qkv, const float* __restrict__ rpeg,
    const float* __restrict__ mask, float* __restrict__ part)
{
  __shared__ float kvs[2 * 128 * HD];   // K-half then V-half, 32 KB
  const int b   = blockIdx.x;
  const int h   = blockIdx.y;
  const int z   = blockIdx.z;           // j-half
  const int tid = threadIdx.x;
  const size_t rowbase = (size_t)b * LW;
  const int j0 = z * 128;               // global j offset of this half

  // stage K (cols 128+h*32) and V (cols 256+h*32) rows [j0, j0+128)
  for (int it = 0; it < 4; ++it) {
    int f = tid + 256 * it;            // 0..1023
    int j = f >> 3, d4 = f & 7;        // local row, float4 idx
    const float* src = qkv + (rowbase + j0 + j) * QKVC + h * HD + d4 * 4;
    *(float4*)(&kvs[j * HD + d4 * 4])            = *(const float4*)(src + 128);
    *(float4*)(&kvs[128 * HD + j * HD + d4 * 4]) = *(const float4*)(src + 256);
  }
  __syncthreads();

  const int i  = tid;
  const int i4 = i >> 2;
  float4 q[8];
  {
    const float4* qr = (const float4*)(qkv + (rowbase + i) * QKVC + h * HD);
#pragma unroll
    for (int d = 0; d < 8; ++d) {
      float4 t = qr[d];
      q[d] = make_float4(t.x * SCALE, t.y * SCALE, t.z * SCALE, t.w * SCALE);
    }
  }
  const float4* rp4base =
      (const float4*)(rpeg + ((size_t)h * 4096 + (size_t)i4 * 64) * 96);
  const float* mrow = mask + ((size_t)b * LW + i) * LW;

  float4 acc[8];
#pragma unroll
  for (int d = 0; d < 8; ++d) acc[d] = make_float4(0.f, 0.f, 0.f, 0.f);
  float m_run = -INFINITY, l_run = 0.f;

  for (int jl = 0; jl < 32; ++jl) {
    const int j4 = z * 32 + jl;
    float4 mv = *(const float4*)(mrow + j4 * 4);
    float mm4 = fmaxf(fmaxf(mv.x, mv.y), fmaxf(mv.z, mv.w));
    if (__all(mm4 < -1e8f)) continue;   // whole j4 block masked for this wave

    const float4* rp = rp4base + (size_t)j4 * 24;          // 96 floats
    const float4* kb = (const float4*)(&kvs[jl * 4 * HD]); // 4 K rows
    float s0 = mv.x, s1 = mv.y, s2 = mv.z, s3 = mv.w;
    float c0 = 0.f;
#pragma unroll
    for (int d = 0; d < 8; ++d) {
      float4 qd = q[d];
      float4 sq = rp[d];                 // scale * q_rpe
      float4 u  = make_float4(qd.x + sq.x, qd.y + sq.y,
                              qd.z + sq.z, qd.w + sq.w);
      c0 += dot4(qd, rp[8 + d]);         // q . k_rpe
      s0 += dot4(u, kb[d]);
      s1 += dot4(u, kb[8 + d]);
      s2 += dot4(u, kb[16 + d]);
      s3 += dot4(u, kb[24 + d]);
    }
    s0 += c0; s1 += c0; s2 += c0; s3 += c0;

    float mm = fmaxf(fmaxf(s0, s1), fmaxf(s2, s3));
    if (mm > m_run) {                    // at most one rescale per j4
      float r = __expf(m_run - mm);
      l_run *= r;
#pragma unroll
      for (int d = 0; d < 8; ++d) {
        acc[d].x *= r; acc[d].y *= r; acc[d].z *= r; acc[d].w *= r;
      }
      m_run = mm;
    }
    float p0 = __expf(s0 - m_run), p1 = __expf(s1 - m_run);
    float p2 = __expf(s2 - m_run), p3 = __expf(s3 - m_run);
    float pool = p0 + p1 + p2 + p3;
    l_run += pool;
    const float4* vb = (const float4*)(&kvs[128 * HD + jl * 4 * HD]);
#pragma unroll
    for (int d = 0; d < 8; ++d) {
      float4 a  = acc[d];
      float4 v0 = vb[d],      v1 = vb[8 + d];
      float4 v2 = vb[16 + d], v3 = vb[24 + d];
      float4 vr = rp[16 + d];
      a.x += p0 * v0.x + p1 * v1.x + p2 * v2.x + p3 * v3.x + pool * vr.x;
      a.y += p0 * v0.y + p1 * v1.y + p2 * v2.y + p3 * v3.y + pool * vr.y;
      a.z += p0 * v0.z + p1 * v1.z + p2 * v2.z + p3 * v3.z + pool * vr.z;
      a.w += p0 * v0.w + p1 * v1.w + p2 * v2.w + p3 * v3.w + pool * vr.w;
      acc[d] = a;
    }
  }

  // partial out: comp-major [z*512+bh][34][i] -> coalesced 256B stores
  float* pb = part + ((size_t)(z * 512 + b * 4 + h) * 34) * 256 + i;
  pb[0]   = m_run;
  pb[256] = l_run;
#pragma unroll
  for (int d = 0; d < 8; ++d) {
    pb[(2 + 4 * d + 0) * 256] = acc[d].x;
    pb[(2 + 4 * d + 1) * 256] = acc[d].y;
    pb[(2 + 4 * d + 2) * 256] = acc[d].z;
    pb[(2 + 4 * d + 3) * 256] = acc[d].w;
  }
}

// ---------------- merge the two j-half partials ----------------
__global__ __launch_bounds__(256) void merge_kernel(
    const float* __restrict__ part, float* __restrict__ out)
{
  const int bh = blockIdx.x;           // 0..511 = b*4+h
  const int i  = threadIdx.x;
  const int b  = bh >> 2, h = bh & 3;
  const float* p0 = part + (size_t)bh * 34 * 256 + i;
  const float* p1 = p0 + (size_t)512 * 34 * 256;
  float m0 = p0[0], l0 = p0[256];
  float m1 = p1[0], l1 = p1[256];
  float M  = fmaxf(m0, m1);            // finite: diagonal j4 always present
  float r0 = __expf(m0 - M);           // expf(-inf)=0 handles empty partials
  float r1 = __expf(m1 - M);
  float inv = 1.f / (l0 * r0 + l1 * r1);
  r0 *= inv; r1 *= inv;
  float* orow = out + ((size_t)b * LW + i) * 128 + h * HD;
#pragma unroll
  for (int d = 0; d < 8; ++d) {
    float4 o;
    o.x = p0[(2 + 4 * d + 0) * 256] * r0 + p1[(2 + 4 * d + 0) * 256] * r1;
    o.y = p0[(2 + 4 * d + 1) * 256] * r0 + p1[(2 + 4 * d + 1) * 256] * r1;
    o.z = p0[(2 + 4 * d + 2) * 256] * r0 + p1[(2 + 4 * d + 2) * 256] * r1;
    o.w = p0[(2 + 4 * d + 3) * 256] * r0 + p1[(2 + 4 * d + 3) * 256] * r1;
    *(float4*)(orow + 4 * d) = o;
  }
}

extern "C" void kernel_launch(void* const* d_in, const int* in_sizes, int n_in,
                              void* d_out, int out_size, void* d_ws, size_t ws_size,
                              hipStream_t stream) {
  (void)in_sizes; (void)n_in; (void)out_size; (void)ws_size;
  const float* x         = (const float*)d_in[0];
  const float* qkv_w     = (const float*)d_in[1];
  const float* qkv_b     = (const float*)d_in[2];
  const float* rpe_table = (const float*)d_in[3];
  const float* proj_w    = (const float*)d_in[4];
  const float* proj_b    = (const float*)d_in[5];
  const float* attn_mask = (const float*)d_in[6];
  const int*   rel_idx   = (const int*)d_in[7];
  float* out = (float*)d_out;

  float* qkvbuf = (float*)d_ws;                          // 32768*384 fp32 (50.3 MB)
  float* rpeg   = qkvbuf + (size_t)ROWS * QKVC;          // 4*4096*96  (6.3 MB)
  float* attnb  = rpeg + (size_t)4 * 4096 * 96;          // 32768*128  (16.8 MB)
  float* part   = attnb + (size_t)ROWS * 128;            // 2*512*34*256 (35.7 MB)

  hipLaunchKernelGGL(rpe_gather_kernel, dim3(6144), dim3(256), 0, stream,
                     rpe_table, rel_idx, rpeg);
  hipLaunchKernelGGL((gemm_nt_bias_v3<QKVC, 128>), dim3(ROWS / 128, QKVC / 128),
                     dim3(256), 0, stream, x, qkv_w, qkv_b, qkvbuf);
  hipLaunchKernelGGL(attn_kernel, dim3(NWIN, 4, 2), dim3(256), 0, stream,
                     qkvbuf, rpeg, attn_mask, part);
  hipLaunchKernelGGL(merge_kernel, dim3(512), dim3(256), 0, stream,
                     part, attnb);
  hipLaunchKernelGGL((gemm_nt_bias_v3<128, 128>), dim3(ROWS / 128, 1),
                     dim3(256), 0, stream, attnb, proj_w, proj_b, out);
}

// Round 4
// 351.011 us; speedup vs baseline: 1.2580x; 1.2580x over previous
//
#include <hip/hip_runtime.h>
#include <math.h>

constexpr int HD    = 32;     // head dim
constexpr int LW    = 256;    // tokens per window (M * N_CAND)
constexpr int NWIN  = 128;    // number of windows (= B_)
constexpr int ROWS  = NWIN * LW;   // 32768 total rows
constexpr int QKVC  = 384;    // qkv columns
constexpr float SCALE = 0.17677669529663687f;  // 1/sqrt(32)

__device__ inline float dot4(const float4 a, const float4 b) {
  return a.x * b.x + a.y * b.y + a.z * b.z + a.w * b.w;
}

// ---------------- RPE gather: rpe_g[h][i4*64+j4][0:96] ----------------
// s in [0,32): scale*q_rpe   [32,64): k_rpe   [64,96): v_rpe
__global__ __launch_bounds__(256) void rpe_gather_kernel(
    const float* __restrict__ tab, const int* __restrict__ rel_idx,
    float* __restrict__ out)
{
  int gid = blockIdx.x * 256 + threadIdx.x;   // 4*4096*96 = 1,572,864 exact
  int s   = gid % 96;
  int hp  = gid / 96;
  int p   = hp & 4095;
  int h   = hp >> 12;
  float v = tab[(size_t)rel_idx[p] * 384 + h * 96 + s];
  if (s < 32) v *= SCALE;
  out[gid] = v;
}

// ---------------- C[M,N] = A[M,K] @ W[N,K]^T + bias (LDS dbuf v3) -----------
template <int N, int K>
__global__ __launch_bounds__(256) void gemm_nt_bias_v3(
    const float* __restrict__ A, const float* __restrict__ W,
    const float* __restrict__ bias, float* __restrict__ C)
{
  constexpr int BK  = 8;
  constexpr int NS  = K / BK;
  constexpr int LDP = 144;
  __shared__ float As[2][BK][LDP];
  __shared__ float Ws[2][BK][LDP];

  const int tid  = threadIdx.x;
  const int tx   = tid & 15;          // n-dir, 8 cols each
  const int ty   = tid >> 4;          // m-dir, 8 rows each
  const int srow = tid >> 1;          // staging row 0..127
  const int skk  = (tid & 1) << 2;    // staging k base: 0 or 4
  const int sphys = srow + ((srow >> 5) << 2);

  const float* Ag = A + ((size_t)blockIdx.x * 128 + srow) * K + skk;
  const float* Wg = W + ((size_t)blockIdx.y * 128 + srow) * K + skk;

  float4 ra = *(const float4*)(Ag);
  float4 rw = *(const float4*)(Wg);
  As[0][skk + 0][sphys] = ra.x; As[0][skk + 1][sphys] = ra.y;
  As[0][skk + 2][sphys] = ra.z; As[0][skk + 3][sphys] = ra.w;
  Ws[0][skk + 0][sphys] = rw.x; Ws[0][skk + 1][sphys] = rw.y;
  Ws[0][skk + 2][sphys] = rw.z; Ws[0][skk + 3][sphys] = rw.w;
  __syncthreads();

  const int mA = ty * 8; const int pA = mA + ((mA >> 5) << 2);
  const int mB = tx * 8; const int pB = mB + ((mB >> 5) << 2);

  float acc[8][8] = {};

  for (int s = 0; s < NS; ++s) {
    const int cur = s & 1;
    if (s + 1 < NS) {
      const int k0 = (s + 1) * BK;
      ra = *(const float4*)(Ag + k0);
      rw = *(const float4*)(Wg + k0);
    }
#pragma unroll
    for (int k = 0; k < BK; ++k) {
      float4 a0 = *(const float4*)&As[cur][k][pA];
      float4 a1 = *(const float4*)&As[cur][k][pA + 4];
      float4 b0 = *(const float4*)&Ws[cur][k][pB];
      float4 b1 = *(const float4*)&Ws[cur][k][pB + 4];
      float av[8] = {a0.x, a0.y, a0.z, a0.w, a1.x, a1.y, a1.z, a1.w};
      float bv[8] = {b0.x, b0.y, b0.z, b0.w, b1.x, b1.y, b1.z, b1.w};
#pragma unroll
      for (int i = 0; i < 8; ++i)
#pragma unroll
        for (int j = 0; j < 8; ++j)
          acc[i][j] += av[i] * bv[j];
    }
    if (s + 1 < NS) {
      const int nxt = (s + 1) & 1;
      As[nxt][skk + 0][sphys] = ra.x; As[nxt][skk + 1][sphys] = ra.y;
      As[nxt][skk + 2][sphys] = ra.z; As[nxt][skk + 3][sphys] = ra.w;
      Ws[nxt][skk + 0][sphys] = rw.x; Ws[nxt][skk + 1][sphys] = rw.y;
      Ws[nxt][skk + 2][sphys] = rw.z; Ws[nxt][skk + 3][sphys] = rw.w;
      __syncthreads();
    }
  }

  const int crow = blockIdx.x * 128 + ty * 8;
  const int ccol = blockIdx.y * 128 + tx * 8;
  float4 bb0 = *(const float4*)(bias + ccol);
  float4 bb1 = *(const float4*)(bias + ccol + 4);
#pragma unroll
  for (int i = 0; i < 8; ++i) {
    float4 r0, r1;
    r0.x = acc[i][0] + bb0.x; r0.y = acc[i][1] + bb0.y;
    r0.z = acc[i][2] + bb0.z; r0.w = acc[i][3] + bb0.w;
    r1.x = acc[i][4] + bb1.x; r1.y = acc[i][5] + bb1.y;
    r1.z = acc[i][6] + bb1.z; r1.w = acc[i][7] + bb1.w;
    *(float4*)(C + (size_t)(crow + i) * N + ccol)     = r0;
    *(float4*)(C + (size_t)(crow + i) * N + ccol + 4) = r1;
  }
}

// ------------- fused window attention (v5: j-split, NATURAL regs) -----------
// grid (NWIN, 4 heads, 2 j-halves), 256 threads. Block z stages only its
// K/V half -> LDS 32 KB.
// REGISTER CONTRACT (hard-learned): do NOT pass a min-waves/EU hint. Both
// (512,4) and (256,4) made hipcc cap VGPR at 64 -> q/acc spilled to scratch
// (FETCH 82->470MB, dur +50%). Natural allocation is ~88 VGPR: no scratch,
// and 88 <= 512/5 still permits ~5 waves/SIMD. With LDS 32KB (5 blocks/CU
// max) and grid 1024 (= 4 blocks/CU), expected residency ~4 blocks =
// 16 waves/CU ~ 50% occupancy -- the latency-hiding v1 (20%, LDS-capped)
// never had.
// Each block computes an online-softmax PARTIAL (m, l, acc[32]) over its 32
// j4 blocks; partials land in workspace (comp-major, coalesced) and a tiny
// merge kernel combines the two halves.
// Hot loop: rescale once per j4 (max of 4 scores); u folded into the d-loop;
// v_rpe fused into the PV pass; wave-uniform __all() skip of masked blocks.
__global__ __launch_bounds__(256) void attn_kernel(
    const float* __restrict__ qkv, const float* __restrict__ rpeg,
    const float* __restrict__ mask, float* __restrict__ part)
{
  __shared__ float kvs[2 * 128 * HD];   // K-half then V-half, 32 KB
  const int b   = blockIdx.x;
  const int h   = blockIdx.y;
  const int z   = blockIdx.z;           // j-half
  const int tid = threadIdx.x;
  const size_t rowbase = (size_t)b * LW;
  const int j0 = z * 128;               // global j offset of this half

  // stage K (cols 128+h*32) and V (cols 256+h*32) rows [j0, j0+128)
  for (int it = 0; it < 4; ++it) {
    int f = tid + 256 * it;            // 0..1023
    int j = f >> 3, d4 = f & 7;        // local row, float4 idx
    const float* src = qkv + (rowbase + j0 + j) * QKVC + h * HD + d4 * 4;
    *(float4*)(&kvs[j * HD + d4 * 4])            = *(const float4*)(src + 128);
    *(float4*)(&kvs[128 * HD + j * HD + d4 * 4]) = *(const float4*)(src + 256);
  }
  __syncthreads();

  const int i  = tid;
  const int i4 = i >> 2;
  float4 q[8];
  {
    const float4* qr = (const float4*)(qkv + (rowbase + i) * QKVC + h * HD);
#pragma unroll
    for (int d = 0; d < 8; ++d) {
      float4 t = qr[d];
      q[d] = make_float4(t.x * SCALE, t.y * SCALE, t.z * SCALE, t.w * SCALE);
    }
  }
  const float4* rp4base =
      (const float4*)(rpeg + ((size_t)h * 4096 + (size_t)i4 * 64) * 96);
  const float* mrow = mask + ((size_t)b * LW + i) * LW;

  float4 acc[8];
#pragma unroll
  for (int d = 0; d < 8; ++d) acc[d] = make_float4(0.f, 0.f, 0.f, 0.f);
  float m_run = -INFINITY, l_run = 0.f;

  for (int jl = 0; jl < 32; ++jl) {
    const int j4 = z * 32 + jl;
    float4 mv = *(const float4*)(mrow + j4 * 4);
    float mm4 = fmaxf(fmaxf(mv.x, mv.y), fmaxf(mv.z, mv.w));
    if (__all(mm4 < -1e8f)) continue;   // whole j4 block masked for this wave

    const float4* rp = rp4base + (size_t)j4 * 24;          // 96 floats
    const float4* kb = (const float4*)(&kvs[jl * 4 * HD]); // 4 K rows
    float s0 = mv.x, s1 = mv.y, s2 = mv.z, s3 = mv.w;
    float c0 = 0.f;
#pragma unroll
    for (int d = 0; d < 8; ++d) {
      float4 qd = q[d];
      float4 sq = rp[d];                 // scale * q_rpe
      float4 u  = make_float4(qd.x + sq.x, qd.y + sq.y,
                              qd.z + sq.z, qd.w + sq.w);
      c0 += dot4(qd, rp[8 + d]);         // q . k_rpe
      s0 += dot4(u, kb[d]);
      s1 += dot4(u, kb[8 + d]);
      s2 += dot4(u, kb[16 + d]);
      s3 += dot4(u, kb[24 + d]);
    }
    s0 += c0; s1 += c0; s2 += c0; s3 += c0;

    float mm = fmaxf(fmaxf(s0, s1), fmaxf(s2, s3));
    if (mm > m_run) {                    // at most one rescale per j4
      float r = __expf(m_run - mm);
      l_run *= r;
#pragma unroll
      for (int d = 0; d < 8; ++d) {
        acc[d].x *= r; acc[d].y *= r; acc[d].z *= r; acc[d].w *= r;
      }
      m_run = mm;
    }
    float p0 = __expf(s0 - m_run), p1 = __expf(s1 - m_run);
    float p2 = __expf(s2 - m_run), p3 = __expf(s3 - m_run);
    float pool = p0 + p1 + p2 + p3;
    l_run += pool;
    const float4* vb = (const float4*)(&kvs[128 * HD + jl * 4 * HD]);
#pragma unroll
    for (int d = 0; d < 8; ++d) {
      float4 a  = acc[d];
      float4 v0 = vb[d],      v1 = vb[8 + d];
      float4 v2 = vb[16 + d], v3 = vb[24 + d];
      float4 vr = rp[16 + d];
      a.x += p0 * v0.x + p1 * v1.x + p2 * v2.x + p3 * v3.x + pool * vr.x;
      a.y += p0 * v0.y + p1 * v1.y + p2 * v2.y + p3 * v3.y + pool * vr.y;
      a.z += p0 * v0.z + p1 * v1.z + p2 * v2.z + p3 * v3.z + pool * vr.z;
      a.w += p0 * v0.w + p1 * v1.w + p2 * v2.w + p3 * v3.w + pool * vr.w;
      acc[d] = a;
    }
  }

  // partial out: comp-major [z*512+bh][34][i] -> coalesced 256B stores
  float* pb = part + ((size_t)(z * 512 + b * 4 + h) * 34) * 256 + i;
  pb[0]   = m_run;
  pb[256] = l_run;
#pragma unroll
  for (int d = 0; d < 8; ++d) {
    pb[(2 + 4 * d + 0) * 256] = acc[d].x;
    pb[(2 + 4 * d + 1) * 256] = acc[d].y;
    pb[(2 + 4 * d + 2) * 256] = acc[d].z;
    pb[(2 + 4 * d + 3) * 256] = acc[d].w;
  }
}

// ---------------- merge the two j-half partials ----------------
__global__ __launch_bounds__(256) void merge_kernel(
    const float* __restrict__ part, float* __restrict__ out)
{
  const int bh = blockIdx.x;           // 0..511 = b*4+h
  const int i  = threadIdx.x;
  const int b  = bh >> 2, h = bh & 3;
  const float* p0 = part + (size_t)bh * 34 * 256 + i;
  const float* p1 = p0 + (size_t)512 * 34 * 256;
  float m0 = p0[0], l0 = p0[256];
  float m1 = p1[0], l1 = p1[256];
  float M  = fmaxf(m0, m1);            // finite: diagonal j4 always present
  float r0 = __expf(m0 - M);           // expf(-inf)=0 handles empty partials
  float r1 = __expf(m1 - M);
  float inv = 1.f / (l0 * r0 + l1 * r1);
  r0 *= inv; r1 *= inv;
  float* orow = out + ((size_t)b * LW + i) * 128 + h * HD;
#pragma unroll
  for (int d = 0; d < 8; ++d) {
    float4 o;
    o.x = p0[(2 + 4 * d + 0) * 256] * r0 + p1[(2 + 4 * d + 0) * 256] * r1;
    o.y = p0[(2 + 4 * d + 1) * 256] * r0 + p1[(2 + 4 * d + 1) * 256] * r1;
    o.z = p0[(2 + 4 * d + 2) * 256] * r0 + p1[(2 + 4 * d + 2) * 256] * r1;
    o.w = p0[(2 + 4 * d + 3) * 256] * r0 + p1[(2 + 4 * d + 3) * 256] * r1;
    *(float4*)(orow + 4 * d) = o;
  }
}

extern "C" void kernel_launch(void* const* d_in, const int* in_sizes, int n_in,
                              void* d_out, int out_size, void* d_ws, size_t ws_size,
                              hipStream_t stream) {
  (void)in_sizes; (void)n_in; (void)out_size; (void)ws_size;
  const float* x         = (const float*)d_in[0];
  const float* qkv_w     = (const float*)d_in[1];
  const float* qkv_b     = (const float*)d_in[2];
  const float* rpe_table = (const float*)d_in[3];
  const float* proj_w    = (const float*)d_in[4];
  const float* proj_b    = (const float*)d_in[5];
  const float* attn_mask = (const float*)d_in[6];
  const int*   rel_idx   = (const int*)d_in[7];
  float* out = (float*)d_out;

  float* qkvbuf = (float*)d_ws;                          // 32768*384 fp32 (50.3 MB)
  float* rpeg   = qkvbuf + (size_t)ROWS * QKVC;          // 4*4096*96  (6.3 MB)
  float* attnb  = rpeg + (size_t)4 * 4096 * 96;          // 32768*128  (16.8 MB)
  float* part   = attnb + (size_t)ROWS * 128;            // 2*512*34*256 (35.7 MB)

  hipLaunchKernelGGL(rpe_gather_kernel, dim3(6144), dim3(256), 0, stream,
                     rpe_table, rel_idx, rpeg);
  hipLaunchKernelGGL((gemm_nt_bias_v3<QKVC, 128>), dim3(ROWS / 128, QKVC / 128),
                     dim3(256), 0, stream, x, qkv_w, qkv_b, qkvbuf);
  hipLaunchKernelGGL(attn_kernel, dim3(NWIN, 4, 2), dim3(256), 0, stream,
                     qkvbuf, rpeg, attn_mask, part);
  hipLaunchKernelGGL(merge_kernel, dim3(512), dim3(256), 0, stream,
                     part, attnb);
  hipLaunchKernelGGL((gemm_nt_bias_v3<128, 128>), dim3(ROWS / 128, 1),
                     dim3(256), 0, stream, attnb, proj_w, proj_b, out);
}